// Round 13
// baseline (529.913 us; speedup 1.0000x reference)
//
#include <hip/hip_runtime.h>
#include <stdint.h>

#define NN    100000
#define NE    1600000
#define IN_F  512
#define HID   256
#define OUTF  16
#define NPAD  100096   // 782 * 128
#define NBK   391      // ceil(NN/256) coarse buckets (dst>>8)
#define EPB   8192     // edges per block in bucket_scatter

typedef unsigned int u32;
typedef __bf16 bfrag  __attribute__((ext_vector_type(8)));
typedef float  f32x4  __attribute__((ext_vector_type(4)));
typedef short  s16x8  __attribute__((ext_vector_type(8)));

__device__ __forceinline__ u32 rotl32(u32 x, int r){ return (x<<r)|(x>>(32-r)); }

// JAX threefry2x32, key=(0,42), counts=(0,i). keep <=> top bit of (x0^x1)==0.
__device__ __forceinline__ bool drop_keep(u32 i){
    const u32 ks0 = 0u, ks1 = 42u, ks2 = 0x1BD11BDAu ^ 0u ^ 42u;
    u32 x0 = 0u + ks0;
    u32 x1 = i  + ks1;
#define TFR(r) { x0 += x1; x1 = rotl32(x1,(r)); x1 ^= x0; }
    TFR(13) TFR(15) TFR(26) TFR(6)   x0 += ks1; x1 += ks2 + 1u;
    TFR(17) TFR(29) TFR(16) TFR(24)  x0 += ks2; x1 += ks0 + 2u;
    TFR(13) TFR(15) TFR(26) TFR(6)   x0 += ks0; x1 += ks1 + 3u;
    TFR(17) TFR(29) TFR(16) TFR(24)  x0 += ks1; x1 += ks2 + 4u;
    TFR(13) TFR(15) TFR(26) TFR(6)   x0 += ks2; x1 += ks0 + 5u;
#undef TFR
    return ((x0 ^ x1) >> 31) == 0u;
}

__device__ __forceinline__ short f2b(float f){
    union { float f; u32 u; } v; v.f = f;
    u32 r = (v.u + 0x7FFFu + ((v.u >> 16) & 1u)) >> 16;   // RNE
    return (short)r;
}
__device__ __forceinline__ float blo(u32 u){ union{u32 u; float f;} v; v.u = u << 16;         return v.f; }
__device__ __forceinline__ float bhi(u32 u){ union{u32 u; float f;} v; v.u = u & 0xFFFF0000u; return v.f; }

__device__ __forceinline__ u32 cvt_pk_bf16(float lo, float hi){
    u32 r;
    asm("v_cvt_pk_bf16_f32 %0, %1, %2" : "=v"(r) : "v"(lo), "v"(hi));
    return r;
}

__device__ __forceinline__ void gll16(const void* g, void* l){
    __builtin_amdgcn_global_load_lds((const __attribute__((address_space(1))) void*)g,
                                     (__attribute__((address_space(3))) void*)l, 16, 0, 0);
}

// ---------------- combined histogram: deg_out (global atomics) + coarse dst buckets ----------------

__global__ __launch_bounds__(256) void build_hist(const int4* __restrict__ src4,
                                                  const int4* __restrict__ dst4,
                                                  int* deg_out, int* __restrict__ bcnt){
    __shared__ int h[NBK];
    int t = threadIdx.x;
    for (int i = t; i < NBK; i += 256) h[i] = 0;
    __syncthreads();
    for (int i = blockIdx.x * 256 + t; i < NE / 4; i += gridDim.x * 256) {
        int4 s = src4[i];
        int4 d = dst4[i];
        atomicAdd(&deg_out[s.x], 1);
        atomicAdd(&deg_out[s.y], 1);
        atomicAdd(&deg_out[s.z], 1);
        atomicAdd(&deg_out[s.w], 1);
        atomicAdd(&h[d.x >> 8], 1);
        atomicAdd(&h[d.y >> 8], 1);
        atomicAdd(&h[d.z >> 8], 1);
        atomicAdd(&h[d.w >> 8], 1);
    }
    __syncthreads();
    for (int i = t; i < NBK; i += 256)
        if (h[i]) atomicAdd(&bcnt[i], h[i]);
}

__global__ __launch_bounds__(256) void finalize_deg(const int* __restrict__ deg_out,
                                                    const int* __restrict__ row_ptr,
                                                    float* isdo, float* isdi){
    int i = blockIdx.x * blockDim.x + threadIdx.x;
    if (i < NN) {
        isdo[i] = rsqrtf(fmaxf((float)deg_out[i], 1.0f));
        isdi[i] = rsqrtf(fmaxf((float)(row_ptr[i + 1] - row_ptr[i]), 1.0f));
    }
}

__global__ __launch_bounds__(512) void bucket_scan(const int* __restrict__ bcnt,
                                                   int* __restrict__ bbase,
                                                   int* __restrict__ bcur,
                                                   int* __restrict__ row_ptr){
    __shared__ int sh[512];
    int t = threadIdx.x;
    int v = (t < NBK) ? bcnt[t] : 0;
    sh[t] = v;
    __syncthreads();
    for (int off = 1; off < 512; off <<= 1) {
        int a = (t >= off) ? sh[t - off] : 0;
        __syncthreads();
        sh[t] += a;
        __syncthreads();
    }
    int excl = sh[t] - v;
    if (t < NBK) { bbase[t] = excl; bcur[t] = excl; }
    if (t == 0)  { bbase[NBK] = NE; row_ptr[NN] = NE; }
}

// Pass B: scatter packed (src<<8 | dst&255) into coarse-bucket regions
__global__ __launch_bounds__(256) void bucket_scatter(const int* __restrict__ src,
                                                      const int* __restrict__ dst,
                                                      int* bcur, u32* __restrict__ tmp){
    __shared__ int lh[NBK];
    __shared__ int lb[NBK];
    int t = threadIdx.x;
    for (int i = t; i < NBK; i += 256) lh[i] = 0;
    __syncthreads();
    const int e0 = blockIdx.x * EPB;
    for (int k = t * 4; k < EPB; k += 1024) {
        int e = e0 + k;
        if (e < NE) {
            int4 d = *(const int4*)(dst + e);
            atomicAdd(&lh[d.x >> 8], 1);
            atomicAdd(&lh[d.y >> 8], 1);
            atomicAdd(&lh[d.z >> 8], 1);
            atomicAdd(&lh[d.w >> 8], 1);
        }
    }
    __syncthreads();
    for (int i = t; i < NBK; i += 256) {
        int c = lh[i];
        if (c) lb[i] = atomicAdd(&bcur[i], c);
        lh[i] = 0;
    }
    __syncthreads();
    for (int k = t * 4; k < EPB; k += 1024) {
        int e = e0 + k;
        if (e < NE) {
            int4 d = *(const int4*)(dst + e);
            int4 s = *(const int4*)(src + e);
            int b0 = d.x >> 8, b1 = d.y >> 8, b2 = d.z >> 8, b3 = d.w >> 8;
            int r0 = atomicAdd(&lh[b0], 1);
            tmp[lb[b0] + r0] = ((u32)s.x << 8) | ((u32)d.x & 255u);
            int r1 = atomicAdd(&lh[b1], 1);
            tmp[lb[b1] + r1] = ((u32)s.y << 8) | ((u32)d.y & 255u);
            int r2 = atomicAdd(&lh[b2], 1);
            tmp[lb[b2] + r2] = ((u32)s.z << 8) | ((u32)d.z & 255u);
            int r3 = atomicAdd(&lh[b3], 1);
            tmp[lb[b3] + r3] = ((u32)s.w << 8) | ((u32)d.w & 255u);
        }
    }
}

// Pass C: per-bucket counting sort by low 8 bits of dst
__global__ __launch_bounds__(256) void bucket_finalize(const u32* __restrict__ tmp,
                                                       const int* __restrict__ bbase,
                                                       int* __restrict__ row_ptr,
                                                       int* __restrict__ col_src){
    __shared__ int h[256];
    __shared__ int wtot[4];
    const int t = threadIdx.x;
    const int b = blockIdx.x;
    const int base = bbase[b];
    const int cnt  = bbase[b + 1] - base;
    h[t] = 0;
    __syncthreads();
    for (int k = t; k < cnt; k += 256)
        atomicAdd(&h[tmp[base + k] & 255u], 1);
    __syncthreads();
    int v = h[t];
    int lane = t & 63, w = t >> 6;
    int s = v;
    #pragma unroll
    for (int off = 1; off < 64; off <<= 1) {
        int u = __shfl_up(s, off);
        if (lane >= off) s += u;
    }
    if (lane == 63) wtot[w] = s;
    __syncthreads();
    int woff = 0;
    #pragma unroll
    for (int i = 0; i < 4; ++i) woff += (i < w) ? wtot[i] : 0;
    int excl = woff + s - v;
    int d = (b << 8) + t;
    if (d < NN) row_ptr[d] = base + excl;
    h[t] = excl;
    __syncthreads();
    for (int k = t; k < cnt; k += 256) {
        u32 p = tmp[base + k];
        int r = atomicAdd(&h[p & 255u], 1);
        col_src[base + r] = (int)(p >> 8);
    }
}

// ---------------- weight transpose+convert ----------------

template<int Kd, int Nd>
__global__ __launch_bounds__(256) void convert_wt(const float* __restrict__ W,
                                                  short* __restrict__ WT){
    int i = blockIdx.x * 256 + threadIdx.x;
    if (i >= Kd * Nd) return;
    int n = i / Kd, k = i - n * Kd;
    WT[i] = f2b(W[(size_t)k * Nd + n]);
}

// ---------------- GEMM1 (round-10 variant): C[128 x 256] = (X fp32) * W1t^T ----------
__global__ __launch_bounds__(256) void gemm_x(const float* __restrict__ X,
                                              const short* __restrict__ BT,
                                              const float* __restrict__ isdo,
                                              short* __restrict__ C){
    __shared__ __align__(16) float As[2 * 4160];
    __shared__ __align__(16) short Bs[2 * 8320];

    const int t = threadIdx.x;
    const int wave = t >> 6, lane = t & 63;
    const int bm = blockIdx.x * 128;

    const float* paA[4];
    #pragma unroll
    for (int g = 0; g < 4; ++g) {
        int row = bm + wave * 32 + g * 8 + (lane >> 3);
        if (row > NN - 1) row = NN - 1;
        paA[g] = X + (size_t)row * IN_F + (lane & 7) * 4;
    }
    const short* paB[4];
    #pragma unroll
    for (int g = 0; g < 4; ++g) {
        int col = (wave * 4 + g) * 16 + (lane >> 2);
        paB[g] = BT + (size_t)col * IN_F + (lane & 3) * 8;
    }

    const int wr = (wave >> 1) * 64;
    const int wc = (wave & 1) * 128;
    const int kq = lane >> 4, r15 = lane & 15;

    f32x4 acc[4][8];
    #pragma unroll
    for (int m = 0; m < 4; ++m)
        #pragma unroll
        for (int n = 0; n < 8; ++n) acc[m][n] = (f32x4)0.0f;

#define STAGE_X(BUF, K0) { \
    float* dA = As + (BUF) * 4160 + wave * 1040; \
    gll16(paA[0] + (K0), dA);       gll16(paA[1] + (K0), dA + 260); \
    gll16(paA[2] + (K0), dA + 520); gll16(paA[3] + (K0), dA + 780); \
    short* dB = Bs + (BUF) * 8320 + wave * 2080; \
    gll16(paB[0] + (K0), dB);        gll16(paB[1] + (K0), dB + 520); \
    gll16(paB[2] + (K0), dB + 1040); gll16(paB[3] + (K0), dB + 1560); }

#define COMPUTE_X(BUF) { \
    const float* AsC = As + (BUF) * 4160; \
    const short* BsC = Bs + (BUF) * 8320; \
    bfrag af[4], bfg[8]; \
    _Pragma("unroll") \
    for (int m = 0; m < 4; ++m) { \
        int r  = wr + m * 16 + r15; \
        const float* ap = AsC + (r >> 3) * 260 + (r & 7) * 32 + kq * 8; \
        float4 f0 = *(const float4*)ap; \
        float4 f1 = *(const float4*)(ap + 4); \
        uint4 q = make_uint4(cvt_pk_bf16(f0.x, f0.y), cvt_pk_bf16(f0.z, f0.w), \
                             cvt_pk_bf16(f1.x, f1.y), cvt_pk_bf16(f1.z, f1.w)); \
        af[m] = *(bfrag*)&q; \
    } \
    _Pragma("unroll") \
    for (int n = 0; n < 8; ++n) { \
        int cg = (wc >> 4) + n; \
        bfg[n] = *(const bfrag*)(BsC + cg * 520 + r15 * 32 + kq * 8); \
    } \
    _Pragma("unroll") \
    for (int m = 0; m < 4; ++m) \
        _Pragma("unroll") \
        for (int n = 0; n < 8; ++n) \
            acc[m][n] = __builtin_amdgcn_mfma_f32_16x16x32_bf16(af[m], bfg[n], acc[m][n], 0, 0, 0); }

    const int NT = IN_F / 32;
    STAGE_X(0, 0);
    int cur = 0;
    for (int tt = 0; tt < NT - 1; ++tt) {
        STAGE_X(cur ^ 1, (tt + 1) * 32);
        asm volatile("s_waitcnt vmcnt(8)" ::: "memory");
        __builtin_amdgcn_s_barrier();
        COMPUTE_X(cur);
        asm volatile("" ::: "memory");
        __builtin_amdgcn_s_barrier();
        cur ^= 1;
    }
    asm volatile("s_waitcnt vmcnt(0)" ::: "memory");
    __builtin_amdgcn_s_barrier();
    COMPUTE_X(cur);
#undef STAGE_X
#undef COMPUTE_X

    const int crow0 = bm + wr + (lane >> 4) * 4;
    const int ccol0 = wc + r15;
    #pragma unroll
    for (int m = 0; m < 4; ++m)
        #pragma unroll
        for (int r = 0; r < 4; ++r) {
            int row = crow0 + m * 16 + r;
            float sc = (row < NN) ? isdo[row] : 0.0f;
            #pragma unroll
            for (int n = 0; n < 8; ++n)
                C[(size_t)row * HID + ccol0 + n * 16] = f2b(acc[m][n][r] * sc);
        }
}

// ---------------- GEMM2 (round-10 variant): C[128 x 256] = A * BT^T (bf16) ------------
template<int K>
__global__ __launch_bounds__(256) void gemm_bt(const short* __restrict__ A,
                                               const short* __restrict__ BT,
                                               short* __restrict__ C){
    __shared__ __align__(16) short As[2 * 4160];
    __shared__ __align__(16) short Bs[2 * 8320];

    const int t = threadIdx.x;
    const int wave = t >> 6, lane = t & 63;
    const int bm = blockIdx.x * 128;

    const short* paA[2];
    #pragma unroll
    for (int g = 0; g < 2; ++g) {
        int row = bm + (wave * 2 + g) * 16 + (lane >> 2);
        paA[g] = A + (size_t)row * K + (lane & 3) * 8;
    }
    const short* paB[4];
    #pragma unroll
    for (int g = 0; g < 4; ++g) {
        int col = (wave * 4 + g) * 16 + (lane >> 2);
        paB[g] = BT + (size_t)col * K + (lane & 3) * 8;
    }

    const int wr = (wave >> 1) * 64;
    const int wc = (wave & 1) * 128;
    const int kq = lane >> 4, r15 = lane & 15;

    f32x4 acc[4][8];
    #pragma unroll
    for (int m = 0; m < 4; ++m)
        #pragma unroll
        for (int n = 0; n < 8; ++n) acc[m][n] = (f32x4)0.0f;

#define STAGE_B(BUF, K0) { \
    short* dA = As + (BUF) * 4160 + wave * 1040; \
    gll16(paA[0] + (K0), dA); gll16(paA[1] + (K0), dA + 520); \
    short* dB = Bs + (BUF) * 8320 + wave * 2080; \
    gll16(paB[0] + (K0), dB);        gll16(paB[1] + (K0), dB + 520); \
    gll16(paB[2] + (K0), dB + 1040); gll16(paB[3] + (K0), dB + 1560); }

#define COMPUTE_B(BUF) { \
    const short* AsC = As + (BUF) * 4160; \
    const short* BsC = Bs + (BUF) * 8320; \
    bfrag af[4], bfg[8]; \
    _Pragma("unroll") \
    for (int m = 0; m < 4; ++m) { \
        int ch = (wr + m * 16) >> 4; \
        af[m] = *(const bfrag*)(AsC + ch * 520 + r15 * 32 + kq * 8); \
    } \
    _Pragma("unroll") \
    for (int n = 0; n < 8; ++n) { \
        int cg = (wc >> 4) + n; \
        bfg[n] = *(const bfrag*)(BsC + cg * 520 + r15 * 32 + kq * 8); \
    } \
    _Pragma("unroll") \
    for (int m = 0; m < 4; ++m) \
        _Pragma("unroll") \
        for (int n = 0; n < 8; ++n) \
            acc[m][n] = __builtin_amdgcn_mfma_f32_16x16x32_bf16(af[m], bfg[n], acc[m][n], 0, 0, 0); }

    const int NT = K / 32;
    STAGE_B(0, 0);
    int cur = 0;
    for (int tt = 0; tt < NT - 1; ++tt) {
        STAGE_B(cur ^ 1, (tt + 1) * 32);
        asm volatile("s_waitcnt vmcnt(6)" ::: "memory");
        __builtin_amdgcn_s_barrier();
        COMPUTE_B(cur);
        asm volatile("" ::: "memory");
        __builtin_amdgcn_s_barrier();
        cur ^= 1;
    }
    asm volatile("s_waitcnt vmcnt(0)" ::: "memory");
    __builtin_amdgcn_s_barrier();
    COMPUTE_B(cur);
#undef STAGE_B
#undef COMPUTE_B

    const int crow0 = bm + wr + (lane >> 4) * 4;
    const int ccol0 = wc + r15;
    #pragma unroll
    for (int m = 0; m < 4; ++m)
        #pragma unroll
        for (int n = 0; n < 8; ++n)
            #pragma unroll
            for (int r = 0; r < 4; ++r)
                C[(size_t)(crow0 + m * 16 + r) * HID + ccol0 + n * 16] = f2b(acc[m][n][r]);
}

// ---------------- gather aggregation: XCD column-sliced (4 slices x 128B) ------------
// slice = blockIdx%4 -> stable per-XCD column slice (XCD = blockIdx%8 round-robin).
// Wave = 1 node at a time (8 nodes per wave); 8 lanes per edge (16B/lane), 8 edges/load.
// Reduce over edge-groups via shfl_xor; dropout via single wave-wide ballot.
template<int MODE>
__global__ __launch_bounds__(256) void gather_agg(const short* __restrict__ H,
                                                  const int* __restrict__ rp,
                                                  const int* __restrict__ cs,
                                                  const float* __restrict__ isdi,
                                                  const float* __restrict__ isdo,
                                                  const float* __restrict__ bias,
                                                  short* __restrict__ out){
    const int lane = threadIdx.x & 63;
    const int wv   = __builtin_amdgcn_readfirstlane((int)(threadIdx.x >> 6));
    const int s    = (int)(blockIdx.x & 3);
    const int bg   = (int)(blockIdx.x >> 2);
    const int eg   = lane >> 3;          // edge sub-index 0..7
    const int p    = lane & 7;           // 16B piece 0..7
    const u32 off  = (u32)(s * 128 + p * 16);
    const char* Hb = (const char*)H;

    const float4 bb0 = *(const float4*)(bias + s * 64 + p * 8);
    const float4 bb1 = *(const float4*)(bias + s * 64 + p * 8 + 4);

#define LD4(sv) (*(const uint4*)(Hb + ((((u32)(sv)) << 9) | off)))
#define ACC(A, u) { A[0]+=blo(u.x); A[1]+=bhi(u.x); A[2]+=blo(u.y); A[3]+=bhi(u.y); \
                    A[4]+=blo(u.z); A[5]+=bhi(u.z); A[6]+=blo(u.w); A[7]+=bhi(u.w); }

    for (int nn = 0; nn < 8; ++nn) {
        const int node = bg * 32 + wv * 8 + nn;   // uniform per wave
        const int e0  = rp[node];
        const int end = rp[node + 1];

        float a[8] = {0,0,0,0,0,0,0,0};
        float b[8] = {0,0,0,0,0,0,0,0};

        int eb = e0;
        for (; eb + 16 <= end; eb += 16) {
            int i0 = cs[eb + eg];
            int i1 = cs[eb + 8 + eg];
            uint4 u0 = LD4(i0);
            uint4 u1 = LD4(i1);
            ACC(a, u0);
            ACC(b, u1);
        }
        if (eb < end) {
            const int last = end - 1;
            int ex = eb + eg;
            int i0 = cs[ex < end ? ex : last];
            uint4 u0 = LD4(i0);
            if (ex >= end) u0 = make_uint4(0u, 0u, 0u, 0u);
            ACC(a, u0);
            if (eb + 8 < end) {
                int ey = eb + 8 + eg;
                int i1 = cs[ey < end ? ey : last];
                uint4 u1 = LD4(i1);
                if (ey >= end) u1 = make_uint4(0u, 0u, 0u, 0u);
                ACC(b, u1);
            }
        }
        #pragma unroll
        for (int j = 0; j < 8; ++j) a[j] += b[j];

        // reduce across edge-groups (lane bits 3..5)
        #pragma unroll
        for (int j = 0; j < 8; ++j) {
            a[j] += __shfl_xor(a[j], 8);
            a[j] += __shfl_xor(a[j], 16);
            a[j] += __shfl_xor(a[j], 32);
        }

        float sd = isdi[node];
        float h[8];
        h[0] = a[0] * sd + bb0.x;  h[1] = a[1] * sd + bb0.y;
        h[2] = a[2] * sd + bb0.z;  h[3] = a[3] * sd + bb0.w;
        h[4] = a[4] * sd + bb1.x;  h[5] = a[5] * sd + bb1.y;
        h[6] = a[6] * sd + bb1.z;  h[7] = a[7] * sd + bb1.w;

        if (MODE == 0) {
            // one threefry per lane covers the slice's 64 cols; broadcast via ballot
            unsigned long long mask =
                __ballot(drop_keep((u32)node * HID + (u32)s * 64 + (u32)lane));
            float so2 = 2.0f * isdo[node];
            #pragma unroll
            for (int j = 0; j < 8; ++j) {
                bool keep = (mask >> (p * 8 + j)) & 1ull;
                h[j] = keep ? fmaxf(h[j], 0.0f) * so2 : 0.0f;
            }
        }

        uint4 wvv;
        wvv.x = ((u32)(unsigned short)f2b(h[1]) << 16) | (u32)(unsigned short)f2b(h[0]);
        wvv.y = ((u32)(unsigned short)f2b(h[3]) << 16) | (u32)(unsigned short)f2b(h[2]);
        wvv.z = ((u32)(unsigned short)f2b(h[5]) << 16) | (u32)(unsigned short)f2b(h[4]);
        wvv.w = ((u32)(unsigned short)f2b(h[7]) << 16) | (u32)(unsigned short)f2b(h[6]);
        if (lane < 8)
            *(uint4*)((char*)out + (size_t)node * 512 + (u32)(s * 128 + lane * 16)) = wvv;
    }
#undef ACC
#undef LD4
}

// ---------------- head (round-10 variant: LDS-staged rows) ----------------
__global__ __launch_bounds__(256) void head_kernel(const short* __restrict__ H2,
                                                   const float* __restrict__ W3,
                                                   const float* __restrict__ b3,
                                                   float* __restrict__ out){
    __shared__ float W3s[HID * OUTF];
    __shared__ short rows[16][HID + 8];
    int t = threadIdx.x;
    for (int i = t; i < HID * OUTF; i += 256) W3s[i] = W3[i];
    const int n0 = blockIdx.x * 16;
    for (int c = t; c < 16 * 32; c += 256) {
        int r = c >> 5, cc = c & 31;
        *(s16x8*)(&rows[r][cc * 8]) = *(const s16x8*)(H2 + (size_t)(n0 + r) * HID + cc * 8);
    }
    __syncthreads();
    int nl = t >> 4, k = t & 15;
    float acc = 0.0f;
    #pragma unroll 4
    for (int j = 0; j < HID; ++j)
        acc += blo((u32)(unsigned short)rows[nl][j]) * W3s[j * OUTF + k];
    out[(size_t)(n0 + nl) * OUTF + k] = acc + b3[k];
}

extern "C" void kernel_launch(void* const* d_in, const int* in_sizes, int n_in,
                              void* d_out, int out_size, void* d_ws, size_t ws_size,
                              hipStream_t stream) {
    const float* X   = (const float*)d_in[0];
    const int*   src = (const int*)  d_in[1];
    const int*   dst = (const int*)  d_in[2];
    const float* W1  = (const float*)d_in[3];
    const float* b1  = (const float*)d_in[4];
    const float* W2  = (const float*)d_in[5];
    const float* b2  = (const float*)d_in[6];
    const float* W3  = (const float*)d_in[7];
    const float* b3  = (const float*)d_in[8];
    float* out = (float*)d_out;

    char* ws = (char*)d_ws;
    size_t o = 0;
    int*   deg_out = (int*)  (ws + o); o += (size_t)NN * 4;
    int*   bcnt    = (int*)  (ws + o); o += (size_t)NBK * 4;       // memset with deg_out
    float* isdo    = (float*)(ws + o); o += (size_t)NN * 4;
    float* isdi    = (float*)(ws + o); o += (size_t)NN * 4;
    int*   row_ptr = (int*)  (ws + o); o += (size_t)(NN + 1) * 4;
    int*   bbase   = (int*)  (ws + o); o += (size_t)(NBK + 1) * 4;
    int*   bcur    = (int*)  (ws + o); o += (size_t)NBK * 4;
    int*   col_src = (int*)  (ws + o); o += (size_t)NE * 4;
    o = (o + 255) & ~(size_t)255;
    short* W1t = (short*)(ws + o); o += (size_t)IN_F * HID * 2;
    short* W2t = (short*)(ws + o); o += (size_t)HID * HID * 2;
    o = (o + 255) & ~(size_t)255;
    short* hA    = (short*)(ws + o); o += (size_t)NPAD * HID * 2;   // h0, later h2
    short* hB    = (short*)(ws + o); o += (size_t)NPAD * HID * 2;   // h1*isdo (tmp alias)
    short* h2pre = (short*)(ws + o); o += (size_t)NPAD * HID * 2;
    if (ws_size < o) return;
    short* h2  = hA;
    u32*   tmp = (u32*)hB;   // alias: tmp consumed (bucket passes) before hB first written

    const size_t zlen = (size_t)NN * 4 + (size_t)NBK * 4;  // deg_out + bcnt contiguous
    hipMemsetAsync(deg_out, 0, zlen, stream);

    // ---- CSR build (bucket sort) + degrees ----
    build_hist<<<256, 256, 0, stream>>>((const int4*)src, (const int4*)dst, deg_out, bcnt);
    bucket_scan<<<1, 512, 0, stream>>>(bcnt, bbase, bcur, row_ptr);
    bucket_scatter<<<(NE + EPB - 1) / EPB, 256, 0, stream>>>(src, dst, bcur, tmp);
    bucket_finalize<<<NBK, 256, 0, stream>>>(tmp, bbase, row_ptr, col_src);
    finalize_deg<<<(NN + 255) / 256, 256, 0, stream>>>(deg_out, row_ptr, isdo, isdi);

    // ---- weight conversions ----
    convert_wt<IN_F, HID><<<IN_F * HID / 256, 256, 0, stream>>>(W1, W1t);
    convert_wt<HID, HID><<<HID * HID / 256, 256, 0, stream>>>(W2, W2t);

    const int GGRID = 4 * (NN / 32);   // 12500 blocks: slice = blk%4, nodes = (blk>>2)*32

    // ---- layer 1 ----
    gemm_x<<<NPAD / 128, 256, 0, stream>>>(X, W1t, isdo, hA);
    gather_agg<0><<<GGRID, 256, 0, stream>>>(hA, row_ptr, col_src, isdi, isdo, b1, hB);

    // ---- layer 2 ----
    gemm_bt<HID><<<NPAD / 128, 256, 0, stream>>>(hB, W2t, h2pre);
    gather_agg<1><<<GGRID, 256, 0, stream>>>(h2pre, row_ptr, col_src, isdi, isdo, b2, h2);

    // ---- head ----
    head_kernel<<<NN / 16, 256, 0, stream>>>(h2, W3, b3, out);
}

// Round 14
// 456.081 us; speedup vs baseline: 1.1619x; 1.1619x over previous
//
#include <hip/hip_runtime.h>
#include <stdint.h>

#define NN    100000
#define NE    1600000
#define IN_F  512
#define HID   256
#define OUTF  16
#define NPAD  100096   // 782 * 128
#define NBK   391      // ceil(NN/256) coarse buckets (dst>>8)
#define EPB   8192     // edges per block in bucket_scatter

typedef unsigned int u32;
typedef __bf16 bfrag  __attribute__((ext_vector_type(8)));
typedef float  f32x4  __attribute__((ext_vector_type(4)));
typedef short  s16x8  __attribute__((ext_vector_type(8)));

__device__ __forceinline__ u32 rotl32(u32 x, int r){ return (x<<r)|(x>>(32-r)); }

// JAX threefry2x32, key=(0,42), counts=(0,i). keep <=> top bit of (x0^x1)==0.
__device__ __forceinline__ bool drop_keep(u32 i){
    const u32 ks0 = 0u, ks1 = 42u, ks2 = 0x1BD11BDAu ^ 0u ^ 42u;
    u32 x0 = 0u + ks0;
    u32 x1 = i  + ks1;
#define TFR(r) { x0 += x1; x1 = rotl32(x1,(r)); x1 ^= x0; }
    TFR(13) TFR(15) TFR(26) TFR(6)   x0 += ks1; x1 += ks2 + 1u;
    TFR(17) TFR(29) TFR(16) TFR(24)  x0 += ks2; x1 += ks0 + 2u;
    TFR(13) TFR(15) TFR(26) TFR(6)   x0 += ks0; x1 += ks1 + 3u;
    TFR(17) TFR(29) TFR(16) TFR(24)  x0 += ks1; x1 += ks2 + 4u;
    TFR(13) TFR(15) TFR(26) TFR(6)   x0 += ks2; x1 += ks0 + 5u;
#undef TFR
    return ((x0 ^ x1) >> 31) == 0u;
}

__device__ __forceinline__ short f2b(float f){
    union { float f; u32 u; } v; v.f = f;
    u32 r = (v.u + 0x7FFFu + ((v.u >> 16) & 1u)) >> 16;   // RNE
    return (short)r;
}
__device__ __forceinline__ float blo(u32 u){ union{u32 u; float f;} v; v.u = u << 16;         return v.f; }
__device__ __forceinline__ float bhi(u32 u){ union{u32 u; float f;} v; v.u = u & 0xFFFF0000u; return v.f; }

__device__ __forceinline__ u32 cvt_pk_bf16(float lo, float hi){
    u32 r;
    asm("v_cvt_pk_bf16_f32 %0, %1, %2" : "=v"(r) : "v"(lo), "v"(hi));
    return r;
}

__device__ __forceinline__ void gll16(const void* g, void* l){
    __builtin_amdgcn_global_load_lds((const __attribute__((address_space(1))) void*)g,
                                     (__attribute__((address_space(3))) void*)l, 16, 0, 0);
}

// ---------------- combined histogram: deg_out (global atomics) + coarse dst buckets ----------------

__global__ __launch_bounds__(256) void build_hist(const int4* __restrict__ src4,
                                                  const int4* __restrict__ dst4,
                                                  int* deg_out, int* __restrict__ bcnt){
    __shared__ int h[NBK];
    int t = threadIdx.x;
    for (int i = t; i < NBK; i += 256) h[i] = 0;
    __syncthreads();
    for (int i = blockIdx.x * 256 + t; i < NE / 4; i += gridDim.x * 256) {
        int4 s = src4[i];
        int4 d = dst4[i];
        atomicAdd(&deg_out[s.x], 1);
        atomicAdd(&deg_out[s.y], 1);
        atomicAdd(&deg_out[s.z], 1);
        atomicAdd(&deg_out[s.w], 1);
        atomicAdd(&h[d.x >> 8], 1);
        atomicAdd(&h[d.y >> 8], 1);
        atomicAdd(&h[d.z >> 8], 1);
        atomicAdd(&h[d.w >> 8], 1);
    }
    __syncthreads();
    for (int i = t; i < NBK; i += 256)
        if (h[i]) atomicAdd(&bcnt[i], h[i]);
}

__global__ __launch_bounds__(256) void finalize_deg(const int* __restrict__ deg_out,
                                                    const int* __restrict__ row_ptr,
                                                    float* isdo, float* isdi){
    int i = blockIdx.x * blockDim.x + threadIdx.x;
    if (i < NN) {
        isdo[i] = rsqrtf(fmaxf((float)deg_out[i], 1.0f));
        isdi[i] = rsqrtf(fmaxf((float)(row_ptr[i + 1] - row_ptr[i]), 1.0f));
    }
}

__global__ __launch_bounds__(512) void bucket_scan(const int* __restrict__ bcnt,
                                                   int* __restrict__ bbase,
                                                   int* __restrict__ bcur,
                                                   int* __restrict__ row_ptr){
    __shared__ int sh[512];
    int t = threadIdx.x;
    int v = (t < NBK) ? bcnt[t] : 0;
    sh[t] = v;
    __syncthreads();
    for (int off = 1; off < 512; off <<= 1) {
        int a = (t >= off) ? sh[t - off] : 0;
        __syncthreads();
        sh[t] += a;
        __syncthreads();
    }
    int excl = sh[t] - v;
    if (t < NBK) { bbase[t] = excl; bcur[t] = excl; }
    if (t == 0)  { bbase[NBK] = NE; row_ptr[NN] = NE; }
}

// Pass B: scatter packed (src<<8 | dst&255) into coarse-bucket regions
__global__ __launch_bounds__(256) void bucket_scatter(const int* __restrict__ src,
                                                      const int* __restrict__ dst,
                                                      int* bcur, u32* __restrict__ tmp){
    __shared__ int lh[NBK];
    __shared__ int lb[NBK];
    int t = threadIdx.x;
    for (int i = t; i < NBK; i += 256) lh[i] = 0;
    __syncthreads();
    const int e0 = blockIdx.x * EPB;
    for (int k = t * 4; k < EPB; k += 1024) {
        int e = e0 + k;
        if (e < NE) {
            int4 d = *(const int4*)(dst + e);
            atomicAdd(&lh[d.x >> 8], 1);
            atomicAdd(&lh[d.y >> 8], 1);
            atomicAdd(&lh[d.z >> 8], 1);
            atomicAdd(&lh[d.w >> 8], 1);
        }
    }
    __syncthreads();
    for (int i = t; i < NBK; i += 256) {
        int c = lh[i];
        if (c) lb[i] = atomicAdd(&bcur[i], c);
        lh[i] = 0;
    }
    __syncthreads();
    for (int k = t * 4; k < EPB; k += 1024) {
        int e = e0 + k;
        if (e < NE) {
            int4 d = *(const int4*)(dst + e);
            int4 s = *(const int4*)(src + e);
            int b0 = d.x >> 8, b1 = d.y >> 8, b2 = d.z >> 8, b3 = d.w >> 8;
            int r0 = atomicAdd(&lh[b0], 1);
            tmp[lb[b0] + r0] = ((u32)s.x << 8) | ((u32)d.x & 255u);
            int r1 = atomicAdd(&lh[b1], 1);
            tmp[lb[b1] + r1] = ((u32)s.y << 8) | ((u32)d.y & 255u);
            int r2 = atomicAdd(&lh[b2], 1);
            tmp[lb[b2] + r2] = ((u32)s.z << 8) | ((u32)d.z & 255u);
            int r3 = atomicAdd(&lh[b3], 1);
            tmp[lb[b3] + r3] = ((u32)s.w << 8) | ((u32)d.w & 255u);
        }
    }
}

// Pass C: per-bucket counting sort by low 8 bits of dst
__global__ __launch_bounds__(256) void bucket_finalize(const u32* __restrict__ tmp,
                                                       const int* __restrict__ bbase,
                                                       int* __restrict__ row_ptr,
                                                       int* __restrict__ col_src){
    __shared__ int h[256];
    __shared__ int wtot[4];
    const int t = threadIdx.x;
    const int b = blockIdx.x;
    const int base = bbase[b];
    const int cnt  = bbase[b + 1] - base;
    h[t] = 0;
    __syncthreads();
    for (int k = t; k < cnt; k += 256)
        atomicAdd(&h[tmp[base + k] & 255u], 1);
    __syncthreads();
    int v = h[t];
    int lane = t & 63, w = t >> 6;
    int s = v;
    #pragma unroll
    for (int off = 1; off < 64; off <<= 1) {
        int u = __shfl_up(s, off);
        if (lane >= off) s += u;
    }
    if (lane == 63) wtot[w] = s;
    __syncthreads();
    int woff = 0;
    #pragma unroll
    for (int i = 0; i < 4; ++i) woff += (i < w) ? wtot[i] : 0;
    int excl = woff + s - v;
    int d = (b << 8) + t;
    if (d < NN) row_ptr[d] = base + excl;
    h[t] = excl;
    __syncthreads();
    for (int k = t; k < cnt; k += 256) {
        u32 p = tmp[base + k];
        int r = atomicAdd(&h[p & 255u], 1);
        col_src[base + r] = (int)(p >> 8);
    }
}

// ---------------- weight transpose+convert (coalesced 64x64 LDS tile) ----------------

template<int Kd, int Nd>
__global__ __launch_bounds__(256) void convert_wt_t(const float* __restrict__ W,
                                                    short* __restrict__ WT){
    __shared__ float tile[64][65];
    const int t = threadIdx.x;
    const int k0 = (int)(blockIdx.x % (Kd / 64)) * 64;
    const int n0 = (int)(blockIdx.x / (Kd / 64)) * 64;
    const int c = t & 63;
    for (int r = t >> 6; r < 64; r += 4)
        tile[r][c] = W[(size_t)(k0 + r) * Nd + n0 + c];
    __syncthreads();
    for (int rn = t >> 6; rn < 64; rn += 4)
        WT[(size_t)(n0 + rn) * Kd + k0 + c] = f2b(tile[c][rn]);
}

// ---------------- GEMM1 (R10): C[128 x 256] = (X fp32) * W1t^T ----------
__global__ __launch_bounds__(256) void gemm_x(const float* __restrict__ X,
                                              const short* __restrict__ BT,
                                              const float* __restrict__ isdo,
                                              short* __restrict__ C){
    __shared__ __align__(16) float As[2 * 4160];
    __shared__ __align__(16) short Bs[2 * 8320];

    const int t = threadIdx.x;
    const int wave = t >> 6, lane = t & 63;
    const int bm = blockIdx.x * 128;

    const float* paA[4];
    #pragma unroll
    for (int g = 0; g < 4; ++g) {
        int row = bm + wave * 32 + g * 8 + (lane >> 3);
        if (row > NN - 1) row = NN - 1;
        paA[g] = X + (size_t)row * IN_F + (lane & 7) * 4;
    }
    const short* paB[4];
    #pragma unroll
    for (int g = 0; g < 4; ++g) {
        int col = (wave * 4 + g) * 16 + (lane >> 2);
        paB[g] = BT + (size_t)col * IN_F + (lane & 3) * 8;
    }

    const int wr = (wave >> 1) * 64;
    const int wc = (wave & 1) * 128;
    const int kq = lane >> 4, r15 = lane & 15;

    f32x4 acc[4][8];
    #pragma unroll
    for (int m = 0; m < 4; ++m)
        #pragma unroll
        for (int n = 0; n < 8; ++n) acc[m][n] = (f32x4)0.0f;

#define STAGE_X(BUF, K0) { \
    float* dA = As + (BUF) * 4160 + wave * 1040; \
    gll16(paA[0] + (K0), dA);       gll16(paA[1] + (K0), dA + 260); \
    gll16(paA[2] + (K0), dA + 520); gll16(paA[3] + (K0), dA + 780); \
    short* dB = Bs + (BUF) * 8320 + wave * 2080; \
    gll16(paB[0] + (K0), dB);        gll16(paB[1] + (K0), dB + 520); \
    gll16(paB[2] + (K0), dB + 1040); gll16(paB[3] + (K0), dB + 1560); }

#define COMPUTE_X(BUF) { \
    const float* AsC = As + (BUF) * 4160; \
    const short* BsC = Bs + (BUF) * 8320; \
    bfrag af[4], bfg[8]; \
    _Pragma("unroll") \
    for (int m = 0; m < 4; ++m) { \
        int r  = wr + m * 16 + r15; \
        const float* ap = AsC + (r >> 3) * 260 + (r & 7) * 32 + kq * 8; \
        float4 f0 = *(const float4*)ap; \
        float4 f1 = *(const float4*)(ap + 4); \
        uint4 q = make_uint4(cvt_pk_bf16(f0.x, f0.y), cvt_pk_bf16(f0.z, f0.w), \
                             cvt_pk_bf16(f1.x, f1.y), cvt_pk_bf16(f1.z, f1.w)); \
        af[m] = *(bfrag*)&q; \
    } \
    _Pragma("unroll") \
    for (int n = 0; n < 8; ++n) { \
        int cg = (wc >> 4) + n; \
        bfg[n] = *(const bfrag*)(BsC + cg * 520 + r15 * 32 + kq * 8); \
    } \
    _Pragma("unroll") \
    for (int m = 0; m < 4; ++m) \
        _Pragma("unroll") \
        for (int n = 0; n < 8; ++n) \
            acc[m][n] = __builtin_amdgcn_mfma_f32_16x16x32_bf16(af[m], bfg[n], acc[m][n], 0, 0, 0); }

    const int NT = IN_F / 32;
    STAGE_X(0, 0);
    int cur = 0;
    for (int tt = 0; tt < NT - 1; ++tt) {
        STAGE_X(cur ^ 1, (tt + 1) * 32);
        asm volatile("s_waitcnt vmcnt(8)" ::: "memory");
        __builtin_amdgcn_s_barrier();
        COMPUTE_X(cur);
        asm volatile("" ::: "memory");
        __builtin_amdgcn_s_barrier();
        cur ^= 1;
    }
    asm volatile("s_waitcnt vmcnt(0)" ::: "memory");
    __builtin_amdgcn_s_barrier();
    COMPUTE_X(cur);
#undef STAGE_X
#undef COMPUTE_X

    const int crow0 = bm + wr + (lane >> 4) * 4;
    const int ccol0 = wc + r15;
    #pragma unroll
    for (int m = 0; m < 4; ++m)
        #pragma unroll
        for (int r = 0; r < 4; ++r) {
            int row = crow0 + m * 16 + r;
            float sc = (row < NN) ? isdo[row] : 0.0f;
            #pragma unroll
            for (int n = 0; n < 8; ++n)
                C[(size_t)row * HID + ccol0 + n * 16] = f2b(acc[m][n][r] * sc);
        }
}

// ---------------- GEMM2 (R10): C[128 x 256] = A * BT^T (bf16) ------------
template<int K>
__global__ __launch_bounds__(256) void gemm_bt(const short* __restrict__ A,
                                               const short* __restrict__ BT,
                                               short* __restrict__ C){
    __shared__ __align__(16) short As[2 * 4160];
    __shared__ __align__(16) short Bs[2 * 8320];

    const int t = threadIdx.x;
    const int wave = t >> 6, lane = t & 63;
    const int bm = blockIdx.x * 128;

    const short* paA[2];
    #pragma unroll
    for (int g = 0; g < 2; ++g) {
        int row = bm + (wave * 2 + g) * 16 + (lane >> 2);
        paA[g] = A + (size_t)row * K + (lane & 3) * 8;
    }
    const short* paB[4];
    #pragma unroll
    for (int g = 0; g < 4; ++g) {
        int col = (wave * 4 + g) * 16 + (lane >> 2);
        paB[g] = BT + (size_t)col * K + (lane & 3) * 8;
    }

    const int wr = (wave >> 1) * 64;
    const int wc = (wave & 1) * 128;
    const int kq = lane >> 4, r15 = lane & 15;

    f32x4 acc[4][8];
    #pragma unroll
    for (int m = 0; m < 4; ++m)
        #pragma unroll
        for (int n = 0; n < 8; ++n) acc[m][n] = (f32x4)0.0f;

#define STAGE_B(BUF, K0) { \
    short* dA = As + (BUF) * 4160 + wave * 1040; \
    gll16(paA[0] + (K0), dA); gll16(paA[1] + (K0), dA + 520); \
    short* dB = Bs + (BUF) * 8320 + wave * 2080; \
    gll16(paB[0] + (K0), dB);        gll16(paB[1] + (K0), dB + 520); \
    gll16(paB[2] + (K0), dB + 1040); gll16(paB[3] + (K0), dB + 1560); }

#define COMPUTE_B(BUF) { \
    const short* AsC = As + (BUF) * 4160; \
    const short* BsC = Bs + (BUF) * 8320; \
    bfrag af[4], bfg[8]; \
    _Pragma("unroll") \
    for (int m = 0; m < 4; ++m) { \
        int ch = (wr + m * 16) >> 4; \
        af[m] = *(const bfrag*)(AsC + ch * 520 + r15 * 32 + kq * 8); \
    } \
    _Pragma("unroll") \
    for (int n = 0; n < 8; ++n) { \
        int cg = (wc >> 4) + n; \
        bfg[n] = *(const bfrag*)(BsC + cg * 520 + r15 * 32 + kq * 8); \
    } \
    _Pragma("unroll") \
    for (int m = 0; m < 4; ++m) \
        _Pragma("unroll") \
        for (int n = 0; n < 8; ++n) \
            acc[m][n] = __builtin_amdgcn_mfma_f32_16x16x32_bf16(af[m], bfg[n], acc[m][n], 0, 0, 0); }

    const int NT = K / 32;
    STAGE_B(0, 0);
    int cur = 0;
    for (int tt = 0; tt < NT - 1; ++tt) {
        STAGE_B(cur ^ 1, (tt + 1) * 32);
        asm volatile("s_waitcnt vmcnt(6)" ::: "memory");
        __builtin_amdgcn_s_barrier();
        COMPUTE_B(cur);
        asm volatile("" ::: "memory");
        __builtin_amdgcn_s_barrier();
        cur ^= 1;
    }
    asm volatile("s_waitcnt vmcnt(0)" ::: "memory");
    __builtin_amdgcn_s_barrier();
    COMPUTE_B(cur);
#undef STAGE_B
#undef COMPUTE_B

    const int crow0 = bm + wr + (lane >> 4) * 4;
    const int ccol0 = wc + r15;
    #pragma unroll
    for (int m = 0; m < 4; ++m)
        #pragma unroll
        for (int n = 0; n < 8; ++n)
            #pragma unroll
            for (int r = 0; r < 4; ++r)
                C[(size_t)(crow0 + m * 16 + r) * HID + ccol0 + n * 16] = f2b(acc[m][n][r]);
}

// ---------------- gather layer 1 (R10 loop): relu+dropout epilogue, bf16 out ----------
__global__ __launch_bounds__(256) void gather_agg0(const short* __restrict__ H,
                                                   const int* __restrict__ rp,
                                                   const int* __restrict__ cs,
                                                   const float* __restrict__ isdi,
                                                   const float* __restrict__ isdo,
                                                   const float* __restrict__ bias,
                                                   short* __restrict__ out){
    const int lane = threadIdx.x & 63;
    const int node = __builtin_amdgcn_readfirstlane((int)(blockIdx.x * 4) + (int)(threadIdx.x >> 6));
    const int e0  = rp[node];
    const int end = rp[node + 1];
    const int sub = lane & 31, half = lane >> 5;
    const u32 off16 = (u32)sub * 16u;
    const char* Hb = (const char*)H;

    float a[8] = {0,0,0,0,0,0,0,0};
    float b[8] = {0,0,0,0,0,0,0,0};

#define LD4(s) (*(const uint4*)(Hb + ((((u32)(s)) << 9) | off16)))
#define ACC(A, u) { A[0]+=blo(u.x); A[1]+=bhi(u.x); A[2]+=blo(u.y); A[3]+=bhi(u.y); \
                    A[4]+=blo(u.z); A[5]+=bhi(u.z); A[6]+=blo(u.w); A[7]+=bhi(u.w); }

    int eb = e0;
    for (; eb + 16 <= end; eb += 16) {
        int t0 = cs[eb+0],  t1 = cs[eb+1],  t2 = cs[eb+2],  t3 = cs[eb+3];
        int t4 = cs[eb+4],  t5 = cs[eb+5],  t6 = cs[eb+6],  t7 = cs[eb+7];
        int t8 = cs[eb+8],  t9 = cs[eb+9],  tA = cs[eb+10], tB = cs[eb+11];
        int tC = cs[eb+12], tD = cs[eb+13], tE = cs[eb+14], tF = cs[eb+15];
        int s0 = half ? t1 : t0;
        int s1 = half ? t3 : t2;
        int s2 = half ? t5 : t4;
        int s3 = half ? t7 : t6;
        int s4 = half ? t9 : t8;
        int s5 = half ? tB : tA;
        int s6 = half ? tD : tC;
        int s7 = half ? tF : tE;
        uint4 u0 = LD4(s0), u1 = LD4(s1), u2 = LD4(s2), u3 = LD4(s3);
        uint4 u4 = LD4(s4), u5 = LD4(s5), u6 = LD4(s6), u7 = LD4(s7);
        ACC(a, u0); ACC(b, u1); ACC(a, u2); ACC(b, u3);
        ACC(a, u4); ACC(b, u5); ACC(a, u6); ACC(b, u7);
    }
    for (; eb + 8 <= end; eb += 8) {
        int t0 = cs[eb+0], t1 = cs[eb+1], t2 = cs[eb+2], t3 = cs[eb+3];
        int t4 = cs[eb+4], t5 = cs[eb+5], t6 = cs[eb+6], t7 = cs[eb+7];
        int s0 = half ? t1 : t0;
        int s1 = half ? t3 : t2;
        int s2 = half ? t5 : t4;
        int s3 = half ? t7 : t6;
        uint4 u0 = LD4(s0), u1 = LD4(s1), u2 = LD4(s2), u3 = LD4(s3);
        ACC(a, u0); ACC(b, u1); ACC(a, u2); ACC(b, u3);
    }
    for (; eb + 2 <= end; eb += 2) {
        int t0 = cs[eb], t1 = cs[eb+1];
        int s = half ? t1 : t0;
        uint4 u = LD4(s);
        ACC(a, u);
    }
    if (eb < end) {
        int s = cs[eb];
        uint4 u = LD4(s);
        if (half == 0) { ACC(a, u); }
    }
#undef ACC
#undef LD4
    #pragma unroll
    for (int j = 0; j < 8; ++j) a[j] += b[j];

    const int srcl = lane >> 1;
    const bool oddq = (lane & 1) != 0;
    float v[4];
    #pragma unroll
    for (int j = 0; j < 4; ++j) {
        float p0 = __shfl(a[j],     srcl);
        float p1 = __shfl(a[j + 4], srcl);
        float q0 = __shfl(a[j],     srcl + 32);
        float q1 = __shfl(a[j + 4], srcl + 32);
        v[j] = oddq ? (p1 + q1) : (p0 + q0);
    }

    float sd = isdi[node];
    float4 bb = *(const float4*)(bias + lane * 4);
    float h0 = v[0] * sd + bb.x;
    float h1 = v[1] * sd + bb.y;
    float h2 = v[2] * sd + bb.z;
    float h3 = v[3] * sd + bb.w;

    float so2 = 2.0f * isdo[node];
    u32 base = (u32)node * HID + (u32)lane * 4;
    h0 = drop_keep(base + 0) ? fmaxf(h0, 0.f) * so2 : 0.f;
    h1 = drop_keep(base + 1) ? fmaxf(h1, 0.f) * so2 : 0.f;
    h2 = drop_keep(base + 2) ? fmaxf(h2, 0.f) * so2 : 0.f;
    h3 = drop_keep(base + 3) ? fmaxf(h3, 0.f) * so2 : 0.f;

    uint2 wv;
    wv.x = ((u32)(unsigned short)f2b(h1) << 16) | (u32)(unsigned short)f2b(h0);
    wv.y = ((u32)(unsigned short)f2b(h3) << 16) | (u32)(unsigned short)f2b(h2);
    *(uint2*)((char*)out + (size_t)node * 512 + (u32)lane * 8u) = wv;
}

// ---------------- gather layer 2 + fused head: out[n][k] = (agg*isdi + b2) @ W3 + b3 ----
__global__ __launch_bounds__(256) void gather_head(const short* __restrict__ H,
                                                   const int* __restrict__ rp,
                                                   const int* __restrict__ cs,
                                                   const float* __restrict__ isdi,
                                                   const float* __restrict__ bias,
                                                   const float* __restrict__ W3,
                                                   const float* __restrict__ b3,
                                                   float* __restrict__ out){
    __shared__ float W3t[OUTF][HID + 4];   // padded rows: lane stride 260 -> 2-way banks
    __shared__ float hs[4][HID];

    const int t = threadIdx.x;
    // stage W3 transposed: thread t owns column c = t, writes all 16 k
    {
        const float4* wrow = (const float4*)(W3 + (size_t)t * OUTF);
        float4 w0 = wrow[0], w1 = wrow[1], w2 = wrow[2], w3 = wrow[3];
        W3t[ 0][t] = w0.x; W3t[ 1][t] = w0.y; W3t[ 2][t] = w0.z; W3t[ 3][t] = w0.w;
        W3t[ 4][t] = w1.x; W3t[ 5][t] = w1.y; W3t[ 6][t] = w1.z; W3t[ 7][t] = w1.w;
        W3t[ 8][t] = w2.x; W3t[ 9][t] = w2.y; W3t[10][t] = w2.z; W3t[11][t] = w2.w;
        W3t[12][t] = w3.x; W3t[13][t] = w3.y; W3t[14][t] = w3.z; W3t[15][t] = w3.w;
    }
    __syncthreads();

    const int lane = threadIdx.x & 63;
    const int wave = (int)(threadIdx.x >> 6);
    const int node = __builtin_amdgcn_readfirstlane((int)(blockIdx.x * 4) + wave);
    const int e0  = rp[node];
    const int end = rp[node + 1];
    const int sub = lane & 31, half = lane >> 5;
    const u32 off16 = (u32)sub * 16u;
    const char* Hb = (const char*)H;

    float a[8] = {0,0,0,0,0,0,0,0};
    float b[8] = {0,0,0,0,0,0,0,0};

#define LD4(s) (*(const uint4*)(Hb + ((((u32)(s)) << 9) | off16)))
#define ACC(A, u) { A[0]+=blo(u.x); A[1]+=bhi(u.x); A[2]+=blo(u.y); A[3]+=bhi(u.y); \
                    A[4]+=blo(u.z); A[5]+=bhi(u.z); A[6]+=blo(u.w); A[7]+=bhi(u.w); }

    int eb = e0;
    for (; eb + 16 <= end; eb += 16) {
        int t0 = cs[eb+0],  t1 = cs[eb+1],  t2 = cs[eb+2],  t3 = cs[eb+3];
        int t4 = cs[eb+4],  t5 = cs[eb+5],  t6 = cs[eb+6],  t7 = cs[eb+7];
        int t8 = cs[eb+8],  t9 = cs[eb+9],  tA = cs[eb+10], tB = cs[eb+11];
        int tC = cs[eb+12], tD = cs[eb+13], tE = cs[eb+14], tF = cs[eb+15];
        int s0 = half ? t1 : t0;
        int s1 = half ? t3 : t2;
        int s2 = half ? t5 : t4;
        int s3 = half ? t7 : t6;
        int s4 = half ? t9 : t8;
        int s5 = half ? tB : tA;
        int s6 = half ? tD : tC;
        int s7 = half ? tF : tE;
        uint4 u0 = LD4(s0), u1 = LD4(s1), u2 = LD4(s2), u3 = LD4(s3);
        uint4 u4 = LD4(s4), u5 = LD4(s5), u6 = LD4(s6), u7 = LD4(s7);
        ACC(a, u0); ACC(b, u1); ACC(a, u2); ACC(b, u3);
        ACC(a, u4); ACC(b, u5); ACC(a, u6); ACC(b, u7);
    }
    for (; eb + 8 <= end; eb += 8) {
        int t0 = cs[eb+0], t1 = cs[eb+1], t2 = cs[eb+2], t3 = cs[eb+3];
        int t4 = cs[eb+4], t5 = cs[eb+5], t6 = cs[eb+6], t7 = cs[eb+7];
        int s0 = half ? t1 : t0;
        int s1 = half ? t3 : t2;
        int s2 = half ? t5 : t4;
        int s3 = half ? t7 : t6;
        uint4 u0 = LD4(s0), u1 = LD4(s1), u2 = LD4(s2), u3 = LD4(s3);
        ACC(a, u0); ACC(b, u1); ACC(a, u2); ACC(b, u3);
    }
    for (; eb + 2 <= end; eb += 2) {
        int t0 = cs[eb], t1 = cs[eb+1];
        int s = half ? t1 : t0;
        uint4 u = LD4(s);
        ACC(a, u);
    }
    if (eb < end) {
        int s = cs[eb];
        uint4 u = LD4(s);
        if (half == 0) { ACC(a, u); }
    }
#undef ACC
#undef LD4
    #pragma unroll
    for (int j = 0; j < 8; ++j) a[j] += b[j];

    const int srcl = lane >> 1;
    const bool oddq = (lane & 1) != 0;
    float v[4];
    #pragma unroll
    for (int j = 0; j < 4; ++j) {
        float p0 = __shfl(a[j],     srcl);
        float p1 = __shfl(a[j + 4], srcl);
        float q0 = __shfl(a[j],     srcl + 32);
        float q1 = __shfl(a[j + 4], srcl + 32);
        v[j] = oddq ? (p1 + q1) : (p0 + q0);
    }

    float sd = isdi[node];
    float4 bb = *(const float4*)(bias + lane * 4);
    float4 hq;
    hq.x = v[0] * sd + bb.x;
    hq.y = v[1] * sd + bb.y;
    hq.z = v[2] * sd + bb.z;
    hq.w = v[3] * sd + bb.w;

    // stage h row (wave-private) and compute the 256x16 head
    *(float4*)&hs[wave][lane * 4] = hq;
    // same-wave RAW on LDS: compiler inserts lgkmcnt wait; no barrier needed.
    const int k   = lane & 15;
    const int grp = lane >> 4;          // 4 groups x 64 cols
    const float* hrow = &hs[wave][grp * 64];
    const float* wrow = &W3t[k][grp * 64];
    float p = 0.0f;
    #pragma unroll
    for (int c4 = 0; c4 < 16; ++c4) {
        float4 hv = *(const float4*)(hrow + c4 * 4);
        float4 wv = *(const float4*)(wrow + c4 * 4);
        p += hv.x * wv.x + hv.y * wv.y + hv.z * wv.z + hv.w * wv.w;
    }
    p += __shfl_xor(p, 16);
    p += __shfl_xor(p, 32);
    if (lane < 16)
        out[(size_t)node * OUTF + lane] = p + b3[lane];
}

extern "C" void kernel_launch(void* const* d_in, const int* in_sizes, int n_in,
                              void* d_out, int out_size, void* d_ws, size_t ws_size,
                              hipStream_t stream) {
    const float* X   = (const float*)d_in[0];
    const int*   src = (const int*)  d_in[1];
    const int*   dst = (const int*)  d_in[2];
    const float* W1  = (const float*)d_in[3];
    const float* b1  = (const float*)d_in[4];
    const float* W2  = (const float*)d_in[5];
    const float* b2  = (const float*)d_in[6];
    const float* W3  = (const float*)d_in[7];
    const float* b3  = (const float*)d_in[8];
    float* out = (float*)d_out;

    char* ws = (char*)d_ws;
    size_t o = 0;
    int*   deg_out = (int*)  (ws + o); o += (size_t)NN * 4;
    int*   bcnt    = (int*)  (ws + o); o += (size_t)NBK * 4;       // memset with deg_out
    float* isdo    = (float*)(ws + o); o += (size_t)NN * 4;
    float* isdi    = (float*)(ws + o); o += (size_t)NN * 4;
    int*   row_ptr = (int*)  (ws + o); o += (size_t)(NN + 1) * 4;
    int*   bbase   = (int*)  (ws + o); o += (size_t)(NBK + 1) * 4;
    int*   bcur    = (int*)  (ws + o); o += (size_t)NBK * 4;
    int*   col_src = (int*)  (ws + o); o += (size_t)NE * 4;
    o = (o + 255) & ~(size_t)255;
    short* W1t = (short*)(ws + o); o += (size_t)IN_F * HID * 2;
    short* W2t = (short*)(ws + o); o += (size_t)HID * HID * 2;
    o = (o + 255) & ~(size_t)255;
    short* hA    = (short*)(ws + o); o += (size_t)NPAD * HID * 2;   // h0
    short* hB    = (short*)(ws + o); o += (size_t)NPAD * HID * 2;   // h1*isdo (tmp alias)
    short* h2pre = (short*)(ws + o); o += (size_t)NPAD * HID * 2;
    if (ws_size < o) return;
    u32* tmp = (u32*)hB;   // alias: tmp consumed (bucket passes) before hB first written

    const size_t zlen = (size_t)NN * 4 + (size_t)NBK * 4;  // deg_out + bcnt contiguous
    hipMemsetAsync(deg_out, 0, zlen, stream);

    // ---- CSR build (bucket sort) + degrees ----
    build_hist<<<256, 256, 0, stream>>>((const int4*)src, (const int4*)dst, deg_out, bcnt);
    bucket_scan<<<1, 512, 0, stream>>>(bcnt, bbase, bcur, row_ptr);
    bucket_scatter<<<(NE + EPB - 1) / EPB, 256, 0, stream>>>(src, dst, bcur, tmp);
    bucket_finalize<<<NBK, 256, 0, stream>>>(tmp, bbase, row_ptr, col_src);
    finalize_deg<<<(NN + 255) / 256, 256, 0, stream>>>(deg_out, row_ptr, isdo, isdi);

    // ---- weight conversions (coalesced tile transpose) ----
    convert_wt_t<IN_F, HID><<<(IN_F / 64) * (HID / 64), 256, 0, stream>>>(W1, W1t);
    convert_wt_t<HID, HID><<<(HID / 64) * (HID / 64), 256, 0, stream>>>(W2, W2t);

    // ---- layer 1 ----
    gemm_x<<<NPAD / 128, 256, 0, stream>>>(X, W1t, isdo, hA);
    gather_agg0<<<NN / 4, 256, 0, stream>>>(hA, row_ptr, col_src, isdi, isdo, b1, hB);

    // ---- layer 2 ----
    gemm_bt<HID><<<NPAD / 128, 256, 0, stream>>>(hB, W2t, h2pre);

    // ---- layer-2 aggregation + fused head ----
    gather_head<<<NN / 4, 256, 0, stream>>>(h2pre, row_ptr, col_src, isdi, b2, W3, b3, out);
}

// Round 15
// 442.823 us; speedup vs baseline: 1.1967x; 1.0299x over previous
//
#include <hip/hip_runtime.h>
#include <stdint.h>

#define NN    100000
#define NE    1600000
#define IN_F  512
#define HID   256
#define OUTF  16
#define NPAD  100096   // 782 * 128
#define NBK   391      // ceil(NN/256) coarse buckets (dst>>8)
#define EPB   8192     // edges per block in bucket_scatter
#define BKCAP 8192     // fixed bucket region capacity (mean 4092, sigma 64 -> safe)

typedef unsigned int u32;
typedef __bf16 bfrag  __attribute__((ext_vector_type(8)));
typedef float  f32x4  __attribute__((ext_vector_type(4)));
typedef short  s16x8  __attribute__((ext_vector_type(8)));

__device__ __forceinline__ u32 rotl32(u32 x, int r){ return (x<<r)|(x>>(32-r)); }

// JAX threefry2x32, key=(0,42), counts=(0,i). keep <=> top bit of (x0^x1)==0.
__device__ __forceinline__ bool drop_keep(u32 i){
    const u32 ks0 = 0u, ks1 = 42u, ks2 = 0x1BD11BDAu ^ 0u ^ 42u;
    u32 x0 = 0u + ks0;
    u32 x1 = i  + ks1;
#define TFR(r) { x0 += x1; x1 = rotl32(x1,(r)); x1 ^= x0; }
    TFR(13) TFR(15) TFR(26) TFR(6)   x0 += ks1; x1 += ks2 + 1u;
    TFR(17) TFR(29) TFR(16) TFR(24)  x0 += ks2; x1 += ks0 + 2u;
    TFR(13) TFR(15) TFR(26) TFR(6)   x0 += ks0; x1 += ks1 + 3u;
    TFR(17) TFR(29) TFR(16) TFR(24)  x0 += ks1; x1 += ks2 + 4u;
    TFR(13) TFR(15) TFR(26) TFR(6)   x0 += ks2; x1 += ks0 + 5u;
#undef TFR
    return ((x0 ^ x1) >> 31) == 0u;
}

__device__ __forceinline__ short f2b(float f){
    union { float f; u32 u; } v; v.f = f;
    u32 r = (v.u + 0x7FFFu + ((v.u >> 16) & 1u)) >> 16;   // RNE
    return (short)r;
}
__device__ __forceinline__ float blo(u32 u){ union{u32 u; float f;} v; v.u = u << 16;         return v.f; }
__device__ __forceinline__ float bhi(u32 u){ union{u32 u; float f;} v; v.u = u & 0xFFFF0000u; return v.f; }

__device__ __forceinline__ u32 cvt_pk_bf16(float lo, float hi){
    u32 r;
    asm("v_cvt_pk_bf16_f32 %0, %1, %2" : "=v"(r) : "v"(lo), "v"(hi));
    return r;
}

__device__ __forceinline__ void gll16(const void* g, void* l){
    __builtin_amdgcn_global_load_lds((const __attribute__((address_space(1))) void*)g,
                                     (__attribute__((address_space(3))) void*)l, 16, 0, 0);
}

// ---------------- single-pass CSR scatter (fixed regions) + deg_out histogram --------
// tmp region for bucket b: [b*BKCAP, b*BKCAP + bcur[b])
__global__ __launch_bounds__(256) void bucket_scatter(const int* __restrict__ src,
                                                      const int* __restrict__ dst,
                                                      int* deg_out,
                                                      int* bcur, u32* __restrict__ tmp){
    __shared__ int lh[NBK];
    __shared__ int lb[NBK];
    int t = threadIdx.x;
    for (int i = t; i < NBK; i += 256) lh[i] = 0;
    __syncthreads();
    const int e0 = blockIdx.x * EPB;
    for (int k = t * 4; k < EPB; k += 1024) {
        int e = e0 + k;
        if (e < NE) {   // e multiple of 4, NE multiple of 4 -> all 4 valid
            int4 d = *(const int4*)(dst + e);
            int4 s = *(const int4*)(src + e);
            atomicAdd(&lh[d.x >> 8], 1);
            atomicAdd(&lh[d.y >> 8], 1);
            atomicAdd(&lh[d.z >> 8], 1);
            atomicAdd(&lh[d.w >> 8], 1);
            atomicAdd(&deg_out[s.x], 1);
            atomicAdd(&deg_out[s.y], 1);
            atomicAdd(&deg_out[s.z], 1);
            atomicAdd(&deg_out[s.w], 1);
        }
    }
    __syncthreads();
    for (int i = t; i < NBK; i += 256) {
        int c = lh[i];
        if (c) lb[i] = atomicAdd(&bcur[i], c);
        lh[i] = 0;
    }
    __syncthreads();
    for (int k = t * 4; k < EPB; k += 1024) {
        int e = e0 + k;
        if (e < NE) {
            int4 d = *(const int4*)(dst + e);
            int4 s = *(const int4*)(src + e);
            int b0 = d.x >> 8, b1 = d.y >> 8, b2 = d.z >> 8, b3 = d.w >> 8;
            int r0 = atomicAdd(&lh[b0], 1);
            tmp[b0 * BKCAP + lb[b0] + r0] = ((u32)s.x << 8) | ((u32)d.x & 255u);
            int r1 = atomicAdd(&lh[b1], 1);
            tmp[b1 * BKCAP + lb[b1] + r1] = ((u32)s.y << 8) | ((u32)d.y & 255u);
            int r2 = atomicAdd(&lh[b2], 1);
            tmp[b2 * BKCAP + lb[b2] + r2] = ((u32)s.z << 8) | ((u32)d.z & 255u);
            int r3 = atomicAdd(&lh[b3], 1);
            tmp[b3 * BKCAP + lb[b3] + r3] = ((u32)s.w << 8) | ((u32)d.w & 255u);
        }
    }
}

// per-bucket counting sort by low 8 bits of dst; emits rp2 (start,end) + isdi
__global__ __launch_bounds__(256) void bucket_finalize(const u32* __restrict__ tmp,
                                                       const int* __restrict__ bcur,
                                                       int2* __restrict__ rp2,
                                                       float* __restrict__ isdi,
                                                       int* __restrict__ col_src){
    __shared__ int h[256];
    __shared__ int wtot[4];
    const int t = threadIdx.x;
    const int b = blockIdx.x;
    const int base = b * BKCAP;
    const int cnt  = bcur[b];
    h[t] = 0;
    __syncthreads();
    for (int k = t; k < cnt; k += 256)
        atomicAdd(&h[tmp[base + k] & 255u], 1);
    __syncthreads();
    int v = h[t];
    int lane = t & 63, w = t >> 6;
    int s = v;
    #pragma unroll
    for (int off = 1; off < 64; off <<= 1) {
        int u = __shfl_up(s, off);
        if (lane >= off) s += u;
    }
    if (lane == 63) wtot[w] = s;
    __syncthreads();
    int woff = 0;
    #pragma unroll
    for (int i = 0; i < 4; ++i) woff += (i < w) ? wtot[i] : 0;
    int excl = woff + s - v;
    int d = (b << 8) + t;
    if (d < NN) {
        rp2[d] = make_int2(base + excl, base + excl + v);
        isdi[d] = rsqrtf(fmaxf((float)v, 1.0f));
    }
    h[t] = excl;
    __syncthreads();
    for (int k = t; k < cnt; k += 256) {
        u32 p = tmp[base + k];
        int r = atomicAdd(&h[p & 255u], 1);
        col_src[base + r] = (int)(p >> 8);
    }
}

__global__ __launch_bounds__(256) void finalize_isdo(const int* __restrict__ deg_out,
                                                     float* isdo){
    int i = blockIdx.x * blockDim.x + threadIdx.x;
    if (i < NN) isdo[i] = rsqrtf(fmaxf((float)deg_out[i], 1.0f));
}

// ---------------- weight transpose+convert (coalesced 64x64 LDS tile) ----------------

template<int Kd, int Nd>
__global__ __launch_bounds__(256) void convert_wt_t(const float* __restrict__ W,
                                                    short* __restrict__ WT){
    __shared__ float tile[64][65];
    const int t = threadIdx.x;
    const int k0 = (int)(blockIdx.x % (Kd / 64)) * 64;
    const int n0 = (int)(blockIdx.x / (Kd / 64)) * 64;
    const int c = t & 63;
    for (int r = t >> 6; r < 64; r += 4)
        tile[r][c] = W[(size_t)(k0 + r) * Nd + n0 + c];
    __syncthreads();
    for (int rn = t >> 6; rn < 64; rn += 4)
        WT[(size_t)(n0 + rn) * Kd + k0 + c] = f2b(tile[c][rn]);
}

// ---------------- GEMM1 (R10): C[128 x 256] = (X fp32) * W1t^T ----------
__global__ __launch_bounds__(256) void gemm_x(const float* __restrict__ X,
                                              const short* __restrict__ BT,
                                              const float* __restrict__ isdo,
                                              short* __restrict__ C){
    __shared__ __align__(16) float As[2 * 4160];
    __shared__ __align__(16) short Bs[2 * 8320];

    const int t = threadIdx.x;
    const int wave = t >> 6, lane = t & 63;
    const int bm = blockIdx.x * 128;

    const float* paA[4];
    #pragma unroll
    for (int g = 0; g < 4; ++g) {
        int row = bm + wave * 32 + g * 8 + (lane >> 3);
        if (row > NN - 1) row = NN - 1;
        paA[g] = X + (size_t)row * IN_F + (lane & 7) * 4;
    }
    const short* paB[4];
    #pragma unroll
    for (int g = 0; g < 4; ++g) {
        int col = (wave * 4 + g) * 16 + (lane >> 2);
        paB[g] = BT + (size_t)col * IN_F + (lane & 3) * 8;
    }

    const int wr = (wave >> 1) * 64;
    const int wc = (wave & 1) * 128;
    const int kq = lane >> 4, r15 = lane & 15;

    f32x4 acc[4][8];
    #pragma unroll
    for (int m = 0; m < 4; ++m)
        #pragma unroll
        for (int n = 0; n < 8; ++n) acc[m][n] = (f32x4)0.0f;

#define STAGE_X(BUF, K0) { \
    float* dA = As + (BUF) * 4160 + wave * 1040; \
    gll16(paA[0] + (K0), dA);       gll16(paA[1] + (K0), dA + 260); \
    gll16(paA[2] + (K0), dA + 520); gll16(paA[3] + (K0), dA + 780); \
    short* dB = Bs + (BUF) * 8320 + wave * 2080; \
    gll16(paB[0] + (K0), dB);        gll16(paB[1] + (K0), dB + 520); \
    gll16(paB[2] + (K0), dB + 1040); gll16(paB[3] + (K0), dB + 1560); }

#define COMPUTE_X(BUF) { \
    const float* AsC = As + (BUF) * 4160; \
    const short* BsC = Bs + (BUF) * 8320; \
    bfrag af[4], bfg[8]; \
    _Pragma("unroll") \
    for (int m = 0; m < 4; ++m) { \
        int r  = wr + m * 16 + r15; \
        const float* ap = AsC + (r >> 3) * 260 + (r & 7) * 32 + kq * 8; \
        float4 f0 = *(const float4*)ap; \
        float4 f1 = *(const float4*)(ap + 4); \
        uint4 q = make_uint4(cvt_pk_bf16(f0.x, f0.y), cvt_pk_bf16(f0.z, f0.w), \
                             cvt_pk_bf16(f1.x, f1.y), cvt_pk_bf16(f1.z, f1.w)); \
        af[m] = *(bfrag*)&q; \
    } \
    _Pragma("unroll") \
    for (int n = 0; n < 8; ++n) { \
        int cg = (wc >> 4) + n; \
        bfg[n] = *(const bfrag*)(BsC + cg * 520 + r15 * 32 + kq * 8); \
    } \
    _Pragma("unroll") \
    for (int m = 0; m < 4; ++m) \
        _Pragma("unroll") \
        for (int n = 0; n < 8; ++n) \
            acc[m][n] = __builtin_amdgcn_mfma_f32_16x16x32_bf16(af[m], bfg[n], acc[m][n], 0, 0, 0); }

    const int NT = IN_F / 32;
    STAGE_X(0, 0);
    int cur = 0;
    for (int tt = 0; tt < NT - 1; ++tt) {
        STAGE_X(cur ^ 1, (tt + 1) * 32);
        asm volatile("s_waitcnt vmcnt(8)" ::: "memory");
        __builtin_amdgcn_s_barrier();
        COMPUTE_X(cur);
        asm volatile("" ::: "memory");
        __builtin_amdgcn_s_barrier();
        cur ^= 1;
    }
    asm volatile("s_waitcnt vmcnt(0)" ::: "memory");
    __builtin_amdgcn_s_barrier();
    COMPUTE_X(cur);
#undef STAGE_X
#undef COMPUTE_X

    const int crow0 = bm + wr + (lane >> 4) * 4;
    const int ccol0 = wc + r15;
    #pragma unroll
    for (int m = 0; m < 4; ++m)
        #pragma unroll
        for (int r = 0; r < 4; ++r) {
            int row = crow0 + m * 16 + r;
            float sc = (row < NN) ? isdo[row] : 0.0f;
            #pragma unroll
            for (int n = 0; n < 8; ++n)
                C[(size_t)row * HID + ccol0 + n * 16] = f2b(acc[m][n][r] * sc);
        }
}

// ---------------- GEMM2 (R10): C[128 x 256] = A * BT^T (bf16) ------------
template<int K>
__global__ __launch_bounds__(256) void gemm_bt(const short* __restrict__ A,
                                               const short* __restrict__ BT,
                                               short* __restrict__ C){
    __shared__ __align__(16) short As[2 * 4160];
    __shared__ __align__(16) short Bs[2 * 8320];

    const int t = threadIdx.x;
    const int wave = t >> 6, lane = t & 63;
    const int bm = blockIdx.x * 128;

    const short* paA[2];
    #pragma unroll
    for (int g = 0; g < 2; ++g) {
        int row = bm + (wave * 2 + g) * 16 + (lane >> 2);
        paA[g] = A + (size_t)row * K + (lane & 3) * 8;
    }
    const short* paB[4];
    #pragma unroll
    for (int g = 0; g < 4; ++g) {
        int col = (wave * 4 + g) * 16 + (lane >> 2);
        paB[g] = BT + (size_t)col * K + (lane & 3) * 8;
    }

    const int wr = (wave >> 1) * 64;
    const int wc = (wave & 1) * 128;
    const int kq = lane >> 4, r15 = lane & 15;

    f32x4 acc[4][8];
    #pragma unroll
    for (int m = 0; m < 4; ++m)
        #pragma unroll
        for (int n = 0; n < 8; ++n) acc[m][n] = (f32x4)0.0f;

#define STAGE_B(BUF, K0) { \
    short* dA = As + (BUF) * 4160 + wave * 1040; \
    gll16(paA[0] + (K0), dA); gll16(paA[1] + (K0), dA + 520); \
    short* dB = Bs + (BUF) * 8320 + wave * 2080; \
    gll16(paB[0] + (K0), dB);        gll16(paB[1] + (K0), dB + 520); \
    gll16(paB[2] + (K0), dB + 1040); gll16(paB[3] + (K0), dB + 1560); }

#define COMPUTE_B(BUF) { \
    const short* AsC = As + (BUF) * 4160; \
    const short* BsC = Bs + (BUF) * 8320; \
    bfrag af[4], bfg[8]; \
    _Pragma("unroll") \
    for (int m = 0; m < 4; ++m) { \
        int ch = (wr + m * 16) >> 4; \
        af[m] = *(const bfrag*)(AsC + ch * 520 + r15 * 32 + kq * 8); \
    } \
    _Pragma("unroll") \
    for (int n = 0; n < 8; ++n) { \
        int cg = (wc >> 4) + n; \
        bfg[n] = *(const bfrag*)(BsC + cg * 520 + r15 * 32 + kq * 8); \
    } \
    _Pragma("unroll") \
    for (int m = 0; m < 4; ++m) \
        _Pragma("unroll") \
        for (int n = 0; n < 8; ++n) \
            acc[m][n] = __builtin_amdgcn_mfma_f32_16x16x32_bf16(af[m], bfg[n], acc[m][n], 0, 0, 0); }

    const int NT = K / 32;
    STAGE_B(0, 0);
    int cur = 0;
    for (int tt = 0; tt < NT - 1; ++tt) {
        STAGE_B(cur ^ 1, (tt + 1) * 32);
        asm volatile("s_waitcnt vmcnt(6)" ::: "memory");
        __builtin_amdgcn_s_barrier();
        COMPUTE_B(cur);
        asm volatile("" ::: "memory");
        __builtin_amdgcn_s_barrier();
        cur ^= 1;
    }
    asm volatile("s_waitcnt vmcnt(0)" ::: "memory");
    __builtin_amdgcn_s_barrier();
    COMPUTE_B(cur);
#undef STAGE_B
#undef COMPUTE_B

    const int crow0 = bm + wr + (lane >> 4) * 4;
    const int ccol0 = wc + r15;
    #pragma unroll
    for (int m = 0; m < 4; ++m)
        #pragma unroll
        for (int n = 0; n < 8; ++n)
            #pragma unroll
            for (int r = 0; r < 4; ++r)
                C[(size_t)(crow0 + m * 16 + r) * HID + ccol0 + n * 16] = f2b(acc[m][n][r]);
}

// ---------------- gather layer 1 (R10 loop): relu+dropout epilogue, bf16 out ----------
__global__ __launch_bounds__(256) void gather_agg0(const short* __restrict__ H,
                                                   const int2* __restrict__ rp2,
                                                   const int* __restrict__ cs,
                                                   const float* __restrict__ isdi,
                                                   const float* __restrict__ isdo,
                                                   const float* __restrict__ bias,
                                                   short* __restrict__ out){
    const int lane = threadIdx.x & 63;
    const int node = __builtin_amdgcn_readfirstlane((int)(blockIdx.x * 4) + (int)(threadIdx.x >> 6));
    const int2 rr = rp2[node];
    const int e0 = rr.x, end = rr.y;
    const int sub = lane & 31, half = lane >> 5;
    const u32 off16 = (u32)sub * 16u;
    const char* Hb = (const char*)H;

    float a[8] = {0,0,0,0,0,0,0,0};
    float b[8] = {0,0,0,0,0,0,0,0};

#define LD4(s) (*(const uint4*)(Hb + ((((u32)(s)) << 9) | off16)))
#define ACC(A, u) { A[0]+=blo(u.x); A[1]+=bhi(u.x); A[2]+=blo(u.y); A[3]+=bhi(u.y); \
                    A[4]+=blo(u.z); A[5]+=bhi(u.z); A[6]+=blo(u.w); A[7]+=bhi(u.w); }

    int eb = e0;
    for (; eb + 16 <= end; eb += 16) {
        int t0 = cs[eb+0],  t1 = cs[eb+1],  t2 = cs[eb+2],  t3 = cs[eb+3];
        int t4 = cs[eb+4],  t5 = cs[eb+5],  t6 = cs[eb+6],  t7 = cs[eb+7];
        int t8 = cs[eb+8],  t9 = cs[eb+9],  tA = cs[eb+10], tB = cs[eb+11];
        int tC = cs[eb+12], tD = cs[eb+13], tE = cs[eb+14], tF = cs[eb+15];
        int s0 = half ? t1 : t0;
        int s1 = half ? t3 : t2;
        int s2 = half ? t5 : t4;
        int s3 = half ? t7 : t6;
        int s4 = half ? t9 : t8;
        int s5 = half ? tB : tA;
        int s6 = half ? tD : tC;
        int s7 = half ? tF : tE;
        uint4 u0 = LD4(s0), u1 = LD4(s1), u2 = LD4(s2), u3 = LD4(s3);
        uint4 u4 = LD4(s4), u5 = LD4(s5), u6 = LD4(s6), u7 = LD4(s7);
        ACC(a, u0); ACC(b, u1); ACC(a, u2); ACC(b, u3);
        ACC(a, u4); ACC(b, u5); ACC(a, u6); ACC(b, u7);
    }
    for (; eb + 8 <= end; eb += 8) {
        int t0 = cs[eb+0], t1 = cs[eb+1], t2 = cs[eb+2], t3 = cs[eb+3];
        int t4 = cs[eb+4], t5 = cs[eb+5], t6 = cs[eb+6], t7 = cs[eb+7];
        int s0 = half ? t1 : t0;
        int s1 = half ? t3 : t2;
        int s2 = half ? t5 : t4;
        int s3 = half ? t7 : t6;
        uint4 u0 = LD4(s0), u1 = LD4(s1), u2 = LD4(s2), u3 = LD4(s3);
        ACC(a, u0); ACC(b, u1); ACC(a, u2); ACC(b, u3);
    }
    for (; eb + 2 <= end; eb += 2) {
        int t0 = cs[eb], t1 = cs[eb+1];
        int s = half ? t1 : t0;
        uint4 u = LD4(s);
        ACC(a, u);
    }
    if (eb < end) {
        int s = cs[eb];
        uint4 u = LD4(s);
        if (half == 0) { ACC(a, u); }
    }
#undef ACC
#undef LD4
    #pragma unroll
    for (int j = 0; j < 8; ++j) a[j] += b[j];

    const int srcl = lane >> 1;
    const bool oddq = (lane & 1) != 0;
    float v[4];
    #pragma unroll
    for (int j = 0; j < 4; ++j) {
        float p0 = __shfl(a[j],     srcl);
        float p1 = __shfl(a[j + 4], srcl);
        float q0 = __shfl(a[j],     srcl + 32);
        float q1 = __shfl(a[j + 4], srcl + 32);
        v[j] = oddq ? (p1 + q1) : (p0 + q0);
    }

    float sd = isdi[node];
    float4 bb = *(const float4*)(bias + lane * 4);
    float h0 = v[0] * sd + bb.x;
    float h1 = v[1] * sd + bb.y;
    float h2 = v[2] * sd + bb.z;
    float h3 = v[3] * sd + bb.w;

    float so2 = 2.0f * isdo[node];
    u32 base = (u32)node * HID + (u32)lane * 4;
    h0 = drop_keep(base + 0) ? fmaxf(h0, 0.f) * so2 : 0.f;
    h1 = drop_keep(base + 1) ? fmaxf(h1, 0.f) * so2 : 0.f;
    h2 = drop_keep(base + 2) ? fmaxf(h2, 0.f) * so2 : 0.f;
    h3 = drop_keep(base + 3) ? fmaxf(h3, 0.f) * so2 : 0.f;

    uint2 wv;
    wv.x = ((u32)(unsigned short)f2b(h1) << 16) | (u32)(unsigned short)f2b(h0);
    wv.y = ((u32)(unsigned short)f2b(h3) << 16) | (u32)(unsigned short)f2b(h2);
    *(uint2*)((char*)out + (size_t)node * 512 + (u32)lane * 8u) = wv;
}

// ---------------- gather layer 2 + fused head ----------------
__global__ __launch_bounds__(256) void gather_head(const short* __restrict__ H,
                                                   const int2* __restrict__ rp2,
                                                   const int* __restrict__ cs,
                                                   const float* __restrict__ isdi,
                                                   const float* __restrict__ bias,
                                                   const float* __restrict__ W3,
                                                   const float* __restrict__ b3,
                                                   float* __restrict__ out){
    __shared__ float W3t[OUTF][HID + 4];
    __shared__ float hs[4][HID];

    const int t = threadIdx.x;
    {
        const float4* wrow = (const float4*)(W3 + (size_t)t * OUTF);
        float4 w0 = wrow[0], w1 = wrow[1], w2 = wrow[2], w3 = wrow[3];
        W3t[ 0][t] = w0.x; W3t[ 1][t] = w0.y; W3t[ 2][t] = w0.z; W3t[ 3][t] = w0.w;
        W3t[ 4][t] = w1.x; W3t[ 5][t] = w1.y; W3t[ 6][t] = w1.z; W3t[ 7][t] = w1.w;
        W3t[ 8][t] = w2.x; W3t[ 9][t] = w2.y; W3t[10][t] = w2.z; W3t[11][t] = w2.w;
        W3t[12][t] = w3.x; W3t[13][t] = w3.y; W3t[14][t] = w3.z; W3t[15][t] = w3.w;
    }
    __syncthreads();

    const int lane = threadIdx.x & 63;
    const int wave = (int)(threadIdx.x >> 6);
    const int node = __builtin_amdgcn_readfirstlane((int)(blockIdx.x * 4) + wave);
    const int2 rr = rp2[node];
    const int e0 = rr.x, end = rr.y;
    const int sub = lane & 31, half = lane >> 5;
    const u32 off16 = (u32)sub * 16u;
    const char* Hb = (const char*)H;

    float a[8] = {0,0,0,0,0,0,0,0};
    float b[8] = {0,0,0,0,0,0,0,0};

#define LD4(s) (*(const uint4*)(Hb + ((((u32)(s)) << 9) | off16)))
#define ACC(A, u) { A[0]+=blo(u.x); A[1]+=bhi(u.x); A[2]+=blo(u.y); A[3]+=bhi(u.y); \
                    A[4]+=blo(u.z); A[5]+=bhi(u.z); A[6]+=blo(u.w); A[7]+=bhi(u.w); }

    int eb = e0;
    for (; eb + 16 <= end; eb += 16) {
        int t0 = cs[eb+0],  t1 = cs[eb+1],  t2 = cs[eb+2],  t3 = cs[eb+3];
        int t4 = cs[eb+4],  t5 = cs[eb+5],  t6 = cs[eb+6],  t7 = cs[eb+7];
        int t8 = cs[eb+8],  t9 = cs[eb+9],  tA = cs[eb+10], tB = cs[eb+11];
        int tC = cs[eb+12], tD = cs[eb+13], tE = cs[eb+14], tF = cs[eb+15];
        int s0 = half ? t1 : t0;
        int s1 = half ? t3 : t2;
        int s2 = half ? t5 : t4;
        int s3 = half ? t7 : t6;
        int s4 = half ? t9 : t8;
        int s5 = half ? tB : tA;
        int s6 = half ? tD : tC;
        int s7 = half ? tF : tE;
        uint4 u0 = LD4(s0), u1 = LD4(s1), u2 = LD4(s2), u3 = LD4(s3);
        uint4 u4 = LD4(s4), u5 = LD4(s5), u6 = LD4(s6), u7 = LD4(s7);
        ACC(a, u0); ACC(b, u1); ACC(a, u2); ACC(b, u3);
        ACC(a, u4); ACC(b, u5); ACC(a, u6); ACC(b, u7);
    }
    for (; eb + 8 <= end; eb += 8) {
        int t0 = cs[eb+0], t1 = cs[eb+1], t2 = cs[eb+2], t3 = cs[eb+3];
        int t4 = cs[eb+4], t5 = cs[eb+5], t6 = cs[eb+6], t7 = cs[eb+7];
        int s0 = half ? t1 : t0;
        int s1 = half ? t3 : t2;
        int s2 = half ? t5 : t4;
        int s3 = half ? t7 : t6;
        uint4 u0 = LD4(s0), u1 = LD4(s1), u2 = LD4(s2), u3 = LD4(s3);
        ACC(a, u0); ACC(b, u1); ACC(a, u2); ACC(b, u3);
    }
    for (; eb + 2 <= end; eb += 2) {
        int t0 = cs[eb], t1 = cs[eb+1];
        int s = half ? t1 : t0;
        uint4 u = LD4(s);
        ACC(a, u);
    }
    if (eb < end) {
        int s = cs[eb];
        uint4 u = LD4(s);
        if (half == 0) { ACC(a, u); }
    }
#undef ACC
#undef LD4
    #pragma unroll
    for (int j = 0; j < 8; ++j) a[j] += b[j];

    const int srcl = lane >> 1;
    const bool oddq = (lane & 1) != 0;
    float v[4];
    #pragma unroll
    for (int j = 0; j < 4; ++j) {
        float p0 = __shfl(a[j],     srcl);
        float p1 = __shfl(a[j + 4], srcl);
        float q0 = __shfl(a[j],     srcl + 32);
        float q1 = __shfl(a[j + 4], srcl + 32);
        v[j] = oddq ? (p1 + q1) : (p0 + q0);
    }

    float sd = isdi[node];
    float4 bb = *(const float4*)(bias + lane * 4);
    float4 hq;
    hq.x = v[0] * sd + bb.x;
    hq.y = v[1] * sd + bb.y;
    hq.z = v[2] * sd + bb.z;
    hq.w = v[3] * sd + bb.w;

    *(float4*)&hs[wave][lane * 4] = hq;
    const int k   = lane & 15;
    const int grp = lane >> 4;
    const float* hrow = &hs[wave][grp * 64];
    const float* wrow = &W3t[k][grp * 64];
    float p = 0.0f;
    #pragma unroll
    for (int c4 = 0; c4 < 16; ++c4) {
        float4 hv = *(const float4*)(hrow + c4 * 4);
        float4 wv = *(const float4*)(wrow + c4 * 4);
        p += hv.x * wv.x + hv.y * wv.y + hv.z * wv.z + hv.w * wv.w;
    }
    p += __shfl_xor(p, 16);
    p += __shfl_xor(p, 32);
    if (lane < 16)
        out[(size_t)node * OUTF + lane] = p + b3[lane];
}

extern "C" void kernel_launch(void* const* d_in, const int* in_sizes, int n_in,
                              void* d_out, int out_size, void* d_ws, size_t ws_size,
                              hipStream_t stream) {
    const float* X   = (const float*)d_in[0];
    const int*   src = (const int*)  d_in[1];
    const int*   dst = (const int*)  d_in[2];
    const float* W1  = (const float*)d_in[3];
    const float* b1  = (const float*)d_in[4];
    const float* W2  = (const float*)d_in[5];
    const float* b2  = (const float*)d_in[6];
    const float* W3  = (const float*)d_in[7];
    const float* b3  = (const float*)d_in[8];
    float* out = (float*)d_out;

    char* ws = (char*)d_ws;
    size_t o = 0;
    int*   deg_out = (int*)  (ws + o); o += (size_t)NN * 4;
    int*   bcur    = (int*)  (ws + o); o += (size_t)NBK * 4;        // memset with deg_out
    float* isdo    = (float*)(ws + o); o += (size_t)NN * 4;
    float* isdi    = (float*)(ws + o); o += (size_t)NN * 4;
    int2*  rp2     = (int2*) (ws + o); o += (size_t)NN * 8;
    int*   col_src = (int*)  (ws + o); o += (size_t)NBK * BKCAP * 4;  // 12.8 MB (segmented)
    o = (o + 255) & ~(size_t)255;
    short* W1t = (short*)(ws + o); o += (size_t)IN_F * HID * 2;
    short* W2t = (short*)(ws + o); o += (size_t)HID * HID * 2;
    o = (o + 255) & ~(size_t)255;
    short* hA    = (short*)(ws + o); o += (size_t)NPAD * HID * 2;   // h0
    short* hB    = (short*)(ws + o); o += (size_t)NPAD * HID * 2;   // h1*isdo (tmp alias)
    short* h2pre = (short*)(ws + o); o += (size_t)NPAD * HID * 2;
    if (ws_size < o) return;
    u32* tmp = (u32*)hB;   // 12.8 MB region, consumed before hB first written

    const size_t zlen = (size_t)NN * 4 + (size_t)NBK * 4;  // deg_out + bcur contiguous
    hipMemsetAsync(deg_out, 0, zlen, stream);

    // ---- CSR build (single-pass scatter into fixed regions) + degrees ----
    bucket_scatter<<<(NE + EPB - 1) / EPB, 256, 0, stream>>>(src, dst, deg_out, bcur, tmp);
    bucket_finalize<<<NBK, 256, 0, stream>>>(tmp, bcur, rp2, isdi, col_src);
    finalize_isdo<<<(NN + 255) / 256, 256, 0, stream>>>(deg_out, isdo);

    // ---- weight conversions (coalesced tile transpose) ----
    convert_wt_t<IN_F, HID><<<(IN_F / 64) * (HID / 64), 256, 0, stream>>>(W1, W1t);
    convert_wt_t<HID, HID><<<(HID / 64) * (HID / 64), 256, 0, stream>>>(W2, W2t);

    // ---- layer 1 ----
    gemm_x<<<NPAD / 128, 256, 0, stream>>>(X, W1t, isdo, hA);
    gather_agg0<<<NN / 4, 256, 0, stream>>>(hA, rp2, col_src, isdi, isdo, b1, hB);

    // ---- layer 2 ----
    gemm_bt<HID><<<NPAD / 128, 256, 0, stream>>>(hB, W2t, h2pre);

    // ---- layer-2 aggregation + fused head ----
    gather_head<<<NN / 4, 256, 0, stream>>>(h2pre, rp2, col_src, isdi, b2, W3, b3, out);
}